// Round 3
// baseline (89.728 us; speedup 1.0000x reference)
//
#include <hip/hip_runtime.h>
#include <hip/hip_bf16.h>

#define NB 32
#define NC 128
#define NW 128
#define NH 128
#define BCH (NB * NC * NH)

// One 64-thread (1-wave) block handles TWO (b,c) channels: half-wave = one
// channel (ch = tid>>5), each lane covers 4 h values (ll, ll+32, ll+64, ll+96).
// Every broadcast LDS read is amortized over 4 h-computations; the two
// half-waves read 2 distinct addresses (channel-1 tile offset by 16B ->
// disjoint bank groups -> conflict-free).
//
// Per-w tile entry: (sA2, sA2*d, m, m*x) with sA2 = sqrt(alpha*log2e), so
//   t'   = fma(-sA2, rh, sA2*d)      => t'^2 = A2*(d-rh)^2
//   mn   = min_w t'^2                (pass A; shift M = -mn >= max_w s2)
//   v    = fma(-t', t', mn)  (<= 0 always -> exp2 never overflows)
//   e1   = m * exp2(v)               (softmax numerator, shift by M)
//   e2   = m * exp2(10v) = m * g1^10 (kappa=10 path; g1^10 via 4 muls)
// Peak kappa term has g=1 (at argmin w) -> no 0/0. Shift cancels in y, y_t;
// w_out = (log2(sum1) - mn) * ln2.
__global__ __launch_bounds__(64) void sci_kernel(
    const void* __restrict__ xp, const void* __restrict__ dp,
    const void* __restrict__ mp, const void* __restrict__ kp,
    void* __restrict__ outp)
{
    const int bid = blockIdx.x;   // 0 .. B*C/2-1
    const int tid = threadIdx.x;  // 0 .. 63
    const int ch  = tid >> 5;     // which of the block's 2 channels
    const int ll  = tid & 31;

    __shared__ float4 tile[2][NW + 1];  // +1 entry: shift ch-1 bank group

    // ---- dtype detection (wave-uniform, deterministic) ----
    const unsigned short* du16 = (const unsigned short*)dp;
    bool is_bf16 = true;
    #pragma unroll
    for (int i = 0; i < 64; i += 2) {
        float v = __uint_as_float(((unsigned int)du16[i]) << 16);
        is_bf16 = is_bf16 && (v >= 0.0f) && (v <= 129.0f);
    }

    // ---- stage 2 channels into LDS (4 w per thread) ----
    const float LOG2E = 1.4426950408889634f;
    #pragma unroll
    for (int j = 0; j < 4; ++j) {
        const int w = ll + 32 * j;
        const int base = (2 * bid + ch) * NW + w;
        float dv, mv, xv, kv;
        if (is_bf16) {
            dv = __bfloat162float(((const __hip_bfloat16*)dp)[base]);
            mv = __bfloat162float(((const __hip_bfloat16*)mp)[base]);
            xv = __bfloat162float(((const __hip_bfloat16*)xp)[base]);
            kv = __bfloat162float(((const __hip_bfloat16*)kp)[w]);
        } else {
            dv = ((const float*)dp)[base];
            mv = ((const float*)mp)[base];
            xv = ((const float*)xp)[base];
            kv = ((const float*)kp)[w];
        }
        float A2  = log1pf(__expf(kv)) * LOG2E;   // softplus(kernel)*log2e
        float sA2 = sqrtf(A2);
        tile[ch][w] = make_float4(sA2, sA2 * dv, mv, mv * xv);
    }
    __syncthreads();

    // ref_t = linspace(0, H, H) -> step H/(H-1)
    float rh[4];
    #pragma unroll
    for (int j = 0; j < 4; ++j) rh[j] = (float)(ll + 32 * j) * (128.0f / 127.0f);

    // ---- pass A: mn[j] = min_w A2*(d-rh_j)^2 ----
    float mn[4] = {3.0e38f, 3.0e38f, 3.0e38f, 3.0e38f};
    #pragma unroll 8
    for (int w = 0; w < NW; ++w) {
        float2 q = *(const float2*)&tile[ch][w];
        #pragma unroll
        for (int j = 0; j < 4; ++j) {
            float t = __builtin_fmaf(-q.x, rh[j], q.y);
            mn[j] = fminf(mn[j], t * t);
        }
    }

    // ---- pass B: both softmax accumulations, 4 h per lane ----
    float s1[4] = {0.f, 0.f, 0.f, 0.f}, a1[4] = {0.f, 0.f, 0.f, 0.f};
    float s2[4] = {0.f, 0.f, 0.f, 0.f}, a2[4] = {0.f, 0.f, 0.f, 0.f};
    #pragma unroll 2
    for (int w = 0; w < NW; ++w) {
        float4 q = tile[ch][w];
        #pragma unroll
        for (int j = 0; j < 4; ++j) {
            float t  = __builtin_fmaf(-q.x, rh[j], q.y);
            float v  = __builtin_fmaf(-t, t, mn[j]);
            float g1 = __builtin_amdgcn_exp2f(v);
            float sq = g1 * g1;
            float p4 = sq * sq;
            float p8 = p4 * p4;
            float g2 = p8 * sq;                 // g1^10 == exp2(10v)
            s1[j] = __builtin_fmaf(q.z, g1, s1[j]);
            a1[j] = __builtin_fmaf(q.w, g1, a1[j]);
            s2[j] = __builtin_fmaf(q.z, g2, s2[j]);
            a2[j] = __builtin_fmaf(q.w, g2, a2[j]);
        }
    }

    const float LN2 = 0.6931471805599453f;
    const int obase = (2 * bid + ch) * NH + ll;
    #pragma unroll
    for (int j = 0; j < 4; ++j) {
        float y  = a1[j] * __builtin_amdgcn_rcpf(s1[j]);
        float wv = (__builtin_amdgcn_logf(s1[j]) - mn[j]) * LN2;
        float yt = a2[j] * __builtin_amdgcn_rcpf(s2[j]);
        const int o = obase + 32 * j;
        if (is_bf16) {
            __hip_bfloat16* o16 = (__hip_bfloat16*)outp;
            o16[o]           = __float2bfloat16(y);
            o16[BCH + o]     = __float2bfloat16(wv);
            o16[2 * BCH + o] = __float2bfloat16(yt);
        } else {
            float* o32 = (float*)outp;
            o32[o]           = y;
            o32[BCH + o]     = wv;
            o32[2 * BCH + o] = yt;
        }
    }
}

extern "C" void kernel_launch(void* const* d_in, const int* in_sizes, int n_in,
                              void* d_out, int out_size, void* d_ws, size_t ws_size,
                              hipStream_t stream) {
    const void* x_t = d_in[0];
    const void* d   = d_in[1];
    const void* m   = d_in[2];
    const void* k   = d_in[3];
    dim3 grid(NB * NC / 2);
    dim3 block(64);
    hipLaunchKernelGGL(sci_kernel, grid, block, 0, stream, x_t, d, m, k, d_out);
}

// Round 4
// 83.105 us; speedup vs baseline: 1.0797x; 1.0797x over previous
//
#include <hip/hip_runtime.h>
#include <hip/hip_bf16.h>

#define NB 32
#define NC 128
#define NW 128
#define NH 128
#define BCH (NB * NC * NH)

// One 64-thread (1-wave) block per (b,c) channel.
// Lane ll = tid&31 covers h in {ll, ll+32, ll+64, ll+96} (4 h per lane);
// half-wave 0 accumulates w in [0,64), half-wave 1 w in [64,128).
// -> 4096 waves total = 16 waves/CU (4/SIMD) for latency hiding, while each
// broadcast LDS read still feeds 4 h-computations. The two half-wave read
// addresses differ by 1024B -> same banks, 2-way aliasing (free).
// Partial min combined across half-waves via shfl_xor(32) BEFORE pass B;
// partial sums combined after pass B.
//
// Math (base 2): tile[w] = (sA2, sA2*d, m, m*x), sA2 = sqrt(softplus(k)*log2e)
//   t'  = fma(-sA2, rh, sA2*d)        => t'^2 = A2*(d-rh)^2
//   mn  = (min_w |t'|)^2              (global over all 128 w)
//   v   = fma(-t', t', mn)  <= 0      -> exp2 never overflows
//   e1  = m * exp2(v)                 (shift M = -mn >= max_w s2)
//   e2  = m * exp2(10v) = m * g1^10   (kappa=10 path, 4 muls)
// Peak kappa term has g1=1 at the argmin w -> no 0/0. Shift cancels in
// y, y_t;  w_out = (log2(sum1) - mn) * ln2.
__global__ __launch_bounds__(64) void sci_kernel(
    const void* __restrict__ xp, const void* __restrict__ dp,
    const void* __restrict__ mp, const void* __restrict__ kp,
    void* __restrict__ outp)
{
    const int bc  = blockIdx.x;   // channel 0 .. B*C-1
    const int tid = threadIdx.x;  // 0 .. 63
    const int ll  = tid & 31;
    const int wbase = (tid >> 5) * 64;   // this half-wave's w range start

    __shared__ float4 tile[NW];

    // ---- dtype detection (wave-uniform, deterministic) ----
    const unsigned short* du16 = (const unsigned short*)dp;
    bool is_bf16 = true;
    #pragma unroll
    for (int i = 0; i < 64; i += 2) {
        float v = __uint_as_float(((unsigned int)du16[i]) << 16);
        is_bf16 = is_bf16 && (v >= 0.0f) && (v <= 129.0f);
    }

    // ---- stage this channel into LDS (2 w per thread) ----
    const float LOG2E = 1.4426950408889634f;
    #pragma unroll
    for (int j = 0; j < 2; ++j) {
        const int w = tid + 64 * j;
        const int base = bc * NW + w;
        float dv, mv, xv, kv;
        if (is_bf16) {
            dv = __bfloat162float(((const __hip_bfloat16*)dp)[base]);
            mv = __bfloat162float(((const __hip_bfloat16*)mp)[base]);
            xv = __bfloat162float(((const __hip_bfloat16*)xp)[base]);
            kv = __bfloat162float(((const __hip_bfloat16*)kp)[w]);
        } else {
            dv = ((const float*)dp)[base];
            mv = ((const float*)mp)[base];
            xv = ((const float*)xp)[base];
            kv = ((const float*)kp)[w];
        }
        float A2  = log1pf(__expf(kv)) * LOG2E;   // softplus(kernel)*log2e
        float sA2 = sqrtf(A2);
        tile[w] = make_float4(sA2, sA2 * dv, mv, mv * xv);
    }
    __syncthreads();   // single-wave block: compiles to a waitcnt, cheap

    // ref_t = linspace(0, H, H) -> step H/(H-1)
    float rh[4];
    #pragma unroll
    for (int j = 0; j < 4; ++j) rh[j] = (float)(ll + 32 * j) * (128.0f / 127.0f);

    // ---- pass A: per-half min_w |t'|, then combine across halves ----
    float mna[4] = {3.0e38f, 3.0e38f, 3.0e38f, 3.0e38f};
    #pragma unroll 8
    for (int i = 0; i < 64; ++i) {
        float2 q = *(const float2*)&tile[wbase + i];
        #pragma unroll
        for (int j = 0; j < 4; ++j) {
            float t = __builtin_fmaf(-q.x, rh[j], q.y);
            mna[j] = fminf(mna[j], fabsf(t));   // abs = free input modifier
        }
    }
    float mn[4];
    #pragma unroll
    for (int j = 0; j < 4; ++j) {
        float o = __shfl_xor(mna[j], 32);
        float a = fminf(mna[j], o);
        mn[j] = a * a;
    }

    // ---- pass B: both softmax partial accumulations over this half's w ----
    float s1[4] = {0.f, 0.f, 0.f, 0.f}, a1[4] = {0.f, 0.f, 0.f, 0.f};
    float s2[4] = {0.f, 0.f, 0.f, 0.f}, a2[4] = {0.f, 0.f, 0.f, 0.f};
    #pragma unroll 2
    for (int i = 0; i < 64; ++i) {
        float4 q = tile[wbase + i];
        #pragma unroll
        for (int j = 0; j < 4; ++j) {
            float t  = __builtin_fmaf(-q.x, rh[j], q.y);
            float v  = __builtin_fmaf(-t, t, mn[j]);
            float g1 = __builtin_amdgcn_exp2f(v);
            float sq = g1 * g1;
            float p4 = sq * sq;
            float p8 = p4 * p4;
            float g2 = p8 * sq;                 // g1^10 == exp2(10v)
            s1[j] = __builtin_fmaf(q.z, g1, s1[j]);
            a1[j] = __builtin_fmaf(q.w, g1, a1[j]);
            s2[j] = __builtin_fmaf(q.z, g2, s2[j]);
            a2[j] = __builtin_fmaf(q.w, g2, a2[j]);
        }
    }

    // ---- combine the two w-halves ----
    #pragma unroll
    for (int j = 0; j < 4; ++j) {
        s1[j] += __shfl_xor(s1[j], 32);
        a1[j] += __shfl_xor(a1[j], 32);
        s2[j] += __shfl_xor(s2[j], 32);
        a2[j] += __shfl_xor(a2[j], 32);
    }

    // ---- epilogue: lanes 0..31 hold full sums; they write all outputs ----
    if (tid < 32) {
        const float LN2 = 0.6931471805599453f;
        const int obase = bc * NH + ll;
        #pragma unroll
        for (int j = 0; j < 4; ++j) {
            float y  = a1[j] * __builtin_amdgcn_rcpf(s1[j]);
            float wv = (__builtin_amdgcn_logf(s1[j]) - mn[j]) * LN2;
            float yt = a2[j] * __builtin_amdgcn_rcpf(s2[j]);
            const int o = obase + 32 * j;
            if (is_bf16) {
                __hip_bfloat16* o16 = (__hip_bfloat16*)outp;
                o16[o]           = __float2bfloat16(y);
                o16[BCH + o]     = __float2bfloat16(wv);
                o16[2 * BCH + o] = __float2bfloat16(yt);
            } else {
                float* o32 = (float*)outp;
                o32[o]           = y;
                o32[BCH + o]     = wv;
                o32[2 * BCH + o] = yt;
            }
        }
    }
}

extern "C" void kernel_launch(void* const* d_in, const int* in_sizes, int n_in,
                              void* d_out, int out_size, void* d_ws, size_t ws_size,
                              hipStream_t stream) {
    const void* x_t = d_in[0];
    const void* d   = d_in[1];
    const void* m   = d_in[2];
    const void* k   = d_in[3];
    dim3 grid(NB * NC);
    dim3 block(64);
    hipLaunchKernelGGL(sci_kernel, grid, block, 0, stream, x_t, d, m, k, d_out);
}